// Round 15
// baseline (460.103 us; speedup 1.0000x reference)
//
#include <hip/hip_runtime.h>
#include <hip/hip_bf16.h>

#define LOG2F_ 0.69314718055994530942f

typedef __attribute__((ext_vector_type(8))) short s8bf;      // 8 bf16 (4 VGPRs)
typedef __attribute__((ext_vector_type(4))) float f32x4;     // MFMA C/D
typedef __attribute__((ext_vector_type(4))) unsigned u32x4;  // 4 packed bf16 pairs

// softplus(x) - log(2), numerically stable
__device__ __forceinline__ float ssp(float x) {
    float e = __expf(-fabsf(x));
    return __logf(1.0f + e) + fmaxf(x, 0.0f) - LOG2F_;
}
__device__ __forceinline__ short bf_hi(float x) {
    __hip_bfloat16 h = __float2bfloat16(x);
    return *reinterpret_cast<short*>(&h);
}
__device__ __forceinline__ float bf_to_f(short s) {
    __hip_bfloat16 h;
    *reinterpret_cast<short*>(&h) = s;
    return __bfloat162float(h);
}
// truncation-split packers (hi rounding irrelevant, lo absorbs it)
__device__ __forceinline__ unsigned pkhi(float a, float b) {
    return (__float_as_uint(a) >> 16) | (__float_as_uint(b) & 0xFFFF0000u);
}
__device__ __forceinline__ unsigned pklo(float a, float b) {
    float ra = a - __uint_as_float(__float_as_uint(a) & 0xFFFF0000u);
    float rb = b - __uint_as_float(__float_as_uint(b) & 0xFFFF0000u);
    return (__float_as_uint(ra) >> 16) | (__float_as_uint(rb) & 0xFFFF0000u);
}

// ---- sort pipeline ----
// pass 1: histogram; atomic RETURN is the intra-bin rank (stored per edge)
__global__ __launch_bounds__(256) void hist_kernel(const int* __restrict__ dst,
                                                   int* __restrict__ hist,
                                                   int* __restrict__ rnk, int E) {
    const int i0 = (blockIdx.x * blockDim.x + threadIdx.x) * 4;
    if (i0 + 3 < E) {
        int4 d = *(const int4*)(dst + i0);
        int4 r;
        r.x = atomicAdd(&hist[d.x], 1);
        r.y = atomicAdd(&hist[d.y], 1);
        r.z = atomicAdd(&hist[d.z], 1);
        r.w = atomicAdd(&hist[d.w], 1);
        *(int4*)(rnk + i0) = r;
    } else {
        for (int j = 0; j < 4; ++j)
            if (i0 + j < E) rnk[i0 + j] = atomicAdd(&hist[dst[i0 + j]], 1);
    }
}

// fused single-block exclusive scan: hist[N] -> cursor[N]
__global__ __launch_bounds__(1024) void scan_kernel(const int* __restrict__ h,
                                                    int* __restrict__ cursor, int N) {
    const int tid  = threadIdx.x;
    const int lane = tid & 63, w = tid >> 6;      // 16 waves
    const int chunk = (N + 1023) >> 10;
    const int s0 = tid * chunk;
    int s = 0;
    for (int j = 0; j < chunk; ++j) { int i = s0 + j; if (i < N) s += h[i]; }
    int inc = s;
    #pragma unroll
    for (int off = 1; off < 64; off <<= 1) {
        int o = __shfl_up(inc, off, 64);
        if (lane >= off) inc += o;
    }
    __shared__ int wsum[16];
    if (lane == 63) wsum[w] = inc;
    __syncthreads();
    if (w == 0 && lane < 16) {
        int v = wsum[lane];
        int wi = v;
        #pragma unroll
        for (int off = 1; off < 16; off <<= 1) {
            int o = __shfl_up(wi, off, 64);
            if (lane >= off) wi += o;
        }
        wsum[lane] = wi - v;   // exclusive wave offset
    }
    __syncthreads();
    int run = wsum[w] + (inc - s);   // exclusive prefix for this thread's chunk
    for (int j = 0; j < chunk; ++j) {
        int i = s0 + j;
        if (i < N) { cursor[i] = run; run += h[i]; }
    }
}

// pass 2 (NO atomics): p = cursor[dst[e]] + rnk[e]; meta[p] = {e, dst}
__global__ __launch_bounds__(256) void meta_kernel(const int* __restrict__ dst,
                                                   const int* __restrict__ cursor,
                                                   const int* __restrict__ rnk,
                                                   int2* __restrict__ meta, int E) {
    const int i0 = (blockIdx.x * blockDim.x + threadIdx.x) * 4;
    if (i0 + 3 < E) {
        int4 d = *(const int4*)(dst + i0);
        int4 r = *(const int4*)(rnk + i0);
        meta[cursor[d.x] + r.x] = make_int2(i0,     d.x);
        meta[cursor[d.y] + r.y] = make_int2(i0 + 1, d.y);
        meta[cursor[d.z] + r.z] = make_int2(i0 + 2, d.z);
        meta[cursor[d.w] + r.w] = make_int2(i0 + 3, d.w);
    } else {
        for (int j = 0; j < 4; ++j)
            if (i0 + j < E) {
                int dd = dst[i0 + j];
                meta[cursor[dd] + rnk[i0 + j]] = make_int2(i0 + j, dd);
            }
    }
}

// weight fragment read: frag (nt,k0i) of matrix at byte base `woff`,
// linear-in-lane -> canonical conflict-free ds_read_b128
#define WFRAG(woff, nt, k0i) \
    (*(const s8bf*)(lds + (woff) + ((((nt) << 1) + (k0i)) << 10) + (lane << 4)))

// ---- edge filter network over SORTED edges (best-known structure) ----
// LDS: [0,32K) split weights | [32K,48K) 4 waves x 4KB X buffers
__global__ __launch_bounds__(256, 3) void edge_kernel(
    const float* __restrict__ bf, const float* __restrict__ eh,
    const float* __restrict__ W1, const float* __restrict__ b1,
    const float* __restrict__ W2, const float* __restrict__ b2,
    const int2* __restrict__ meta,
    float* __restrict__ sums, int E)
{
    __shared__ __align__(16) unsigned char lds[49152];

    const int tid  = threadIdx.x;
    const int lane = tid & 63;
    const int wv   = tid >> 6;
    const int g    = lane >> 4;
    const int n16  = lane & 15;

    // ---- init: build W1/W2 bf16-split B-fragments into LDS ----
    {
        float* wst = (float*)(lds + 32768);
        for (int i = tid; i < 4096; i += 256) wst[i] = W1[i];
        __syncthreads();
        for (int u = tid; u < 512; u += 256) {
            const int f = u >> 6, nt = f >> 1, k0i = f & 1;
            const int gg = (u >> 4) & 3, nn = u & 15;
            s8bf hi, lo;
            #pragma unroll
            for (int j = 0; j < 8; ++j) {
                float v = wst[(k0i * 32 + gg * 8 + j) * 64 + nt * 16 + nn];
                short h = bf_hi(v);
                hi[j] = h; lo[j] = bf_hi(v - bf_to_f(h));
            }
            *(s8bf*)(lds + (u << 4)) = hi;
            *(s8bf*)(lds + 8192 + (u << 4)) = lo;
        }
        __syncthreads();
        for (int i = tid; i < 4096; i += 256) wst[i] = W2[i];
        __syncthreads();
        for (int u = tid; u < 512; u += 256) {
            const int f = u >> 6, nt = f >> 1, k0i = f & 1;
            const int gg = (u >> 4) & 3, nn = u & 15;
            s8bf hi, lo;
            #pragma unroll
            for (int j = 0; j < 8; ++j) {
                float v = wst[(k0i * 32 + gg * 8 + j) * 64 + nt * 16 + nn];
                short h = bf_hi(v);
                hi[j] = h; lo[j] = bf_hi(v - bf_to_f(h));
            }
            *(s8bf*)(lds + 16384 + (u << 4)) = hi;
            *(s8bf*)(lds + 24576 + (u << 4)) = lo;
        }
        __syncthreads();   // last barrier — main loop is barrier-free
    }

    float b1v[4], b2v[4];
    #pragma unroll
    for (int nt = 0; nt < 4; ++nt) { b1v[nt] = b1[nt*16 + n16]; b2v[nt] = b2[nt*16 + n16]; }

    unsigned char* wb = lds + 32768 + (wv << 12);
    char* Xh = (char*)wb;
    char* Xl = (char*)wb + 2048;

    const int r4   = lane >> 2;
    const int c16  = (lane & 3) << 4;
    const int s0   = (lane & 3) << 1;
    const int crow = g << 2;
    const int sw_n = (n16 & 7) << 4;

    const int wave_id = (blockIdx.x << 2) + wv;
    const int nwaves  = gridDim.x << 2;
    const int ntiles  = (E + 15) >> 4;
    const int lastE   = E - 1;

    // ---- prologue: meta 2-deep (coalesced int2), first tile's bf rows ----
    int eiv0 = 0, eiv1 = 0, dsv0 = 0, dsv1 = 0;
    float xs[16];
    {
        const int t1 = wave_id + nwaves;
        if (lane < 16) {
            if (wave_id < ntiles) {
                const int2 mv = meta[min(wave_id * 16 + lane, lastE)];
                eiv0 = mv.x; dsv0 = mv.y;
            }
            if (t1 < ntiles) {
                const int2 mv = meta[min(t1 * 16 + lane, lastE)];
                eiv1 = mv.x; dsv1 = mv.y;
            }
        }
        if (wave_id < ntiles) {
            const int ri = __shfl(eiv0, r4, 64);
            const size_t roff = (size_t)(unsigned)ri * 64 + c16;
            *(float4*)&xs[0]  = *(const float4*)(bf + roff);
            *(float4*)&xs[4]  = *(const float4*)(bf + roff + 4);
            *(float4*)&xs[8]  = *(const float4*)(bf + roff + 8);
            *(float4*)&xs[12] = *(const float4*)(bf + roff + 12);
        }
    }

    for (int t = wave_id; t < ntiles; t += nwaves) {
        const int base = t << 4;

        // ---- truncation-split current X, stage to LDS (packed u32) ----
        u32x4 hv0, hv1, lv0, lv1;
        #pragma unroll
        for (int j = 0; j < 4; ++j) {
            hv0[j] = pkhi(xs[2*j],     xs[2*j + 1]);
            lv0[j] = pklo(xs[2*j],     xs[2*j + 1]);
            hv1[j] = pkhi(xs[8 + 2*j], xs[8 + 2*j + 1]);
            lv1[j] = pklo(xs[8 + 2*j], xs[8 + 2*j + 1]);
        }
        {
            const int sw = (r4 & 7) << 4;
            const int a0 = r4 * 128 + ((s0 << 4) ^ sw);
            const int a1 = r4 * 128 + (((s0 + 1) << 4) ^ sw);
            *(u32x4*)(Xh + a0) = hv0;  *(u32x4*)(Xh + a1) = hv1;
            *(u32x4*)(Xl + a0) = lv0;  *(u32x4*)(Xl + a1) = lv1;
        }

        // ---- eh loads for THIS tile (scalar row base via readlane) ----
        float evs[16];
        #pragma unroll
        for (int e = 0; e < 16; ++e) {
            const int ei = __builtin_amdgcn_readlane(eiv0, e);
            evs[e] = eh[(size_t)(unsigned)ei * 64 + lane];
        }

        // ---- prefetch next tile's bf rows ----
        const int tn1 = t + nwaves, tn2 = t + 2 * nwaves;
        if (tn1 < ntiles) {
            const int ri = __shfl(eiv1, r4, 64);
            const size_t roff = (size_t)(unsigned)ri * 64 + c16;
            *(float4*)&xs[0]  = *(const float4*)(bf + roff);
            *(float4*)&xs[4]  = *(const float4*)(bf + roff + 4);
            *(float4*)&xs[8]  = *(const float4*)(bf + roff + 8);
            *(float4*)&xs[12] = *(const float4*)(bf + roff + 12);
        }

        // ---- advance meta pipeline (coalesced, 2-deep) ----
        int eiv_n = 0, dsv_n = 0;
        if (lane < 16 && tn2 < ntiles) {
            const int2 mv = meta[min(tn2 * 16 + lane, lastE)];
            eiv_n = mv.x; dsv_n = mv.y;
        }

        // ---- matmul 1: X @ W1 (hh + hl + lh); B-frags from LDS ----
        f32x4 acc[4];
        #pragma unroll
        for (int nt = 0; nt < 4; ++nt) acc[nt] = (f32x4){0.f, 0.f, 0.f, 0.f};
        #pragma unroll
        for (int k0i = 0; k0i < 2; ++k0i) {
            const int ab = (n16 << 7) + (((((k0i << 2) + g)) << 4) ^ sw_n);
            s8bf ah = *(s8bf*)(Xh + ab);
            s8bf al = *(s8bf*)(Xl + ab);
            s8bf wh0 = WFRAG(0, 0, k0i), wh1 = WFRAG(0, 1, k0i),
                 wh2 = WFRAG(0, 2, k0i), wh3 = WFRAG(0, 3, k0i);
            s8bf wl0 = WFRAG(8192, 0, k0i), wl1 = WFRAG(8192, 1, k0i),
                 wl2 = WFRAG(8192, 2, k0i), wl3 = WFRAG(8192, 3, k0i);
            __builtin_amdgcn_s_setprio(1);
            acc[0] = __builtin_amdgcn_mfma_f32_16x16x32_bf16(ah, wh0, acc[0], 0, 0, 0);
            acc[0] = __builtin_amdgcn_mfma_f32_16x16x32_bf16(ah, wl0, acc[0], 0, 0, 0);
            acc[0] = __builtin_amdgcn_mfma_f32_16x16x32_bf16(al, wh0, acc[0], 0, 0, 0);
            acc[1] = __builtin_amdgcn_mfma_f32_16x16x32_bf16(ah, wh1, acc[1], 0, 0, 0);
            acc[1] = __builtin_amdgcn_mfma_f32_16x16x32_bf16(ah, wl1, acc[1], 0, 0, 0);
            acc[1] = __builtin_amdgcn_mfma_f32_16x16x32_bf16(al, wh1, acc[1], 0, 0, 0);
            acc[2] = __builtin_amdgcn_mfma_f32_16x16x32_bf16(ah, wh2, acc[2], 0, 0, 0);
            acc[2] = __builtin_amdgcn_mfma_f32_16x16x32_bf16(ah, wl2, acc[2], 0, 0, 0);
            acc[2] = __builtin_amdgcn_mfma_f32_16x16x32_bf16(al, wh2, acc[2], 0, 0, 0);
            acc[3] = __builtin_amdgcn_mfma_f32_16x16x32_bf16(ah, wh3, acc[3], 0, 0, 0);
            acc[3] = __builtin_amdgcn_mfma_f32_16x16x32_bf16(ah, wl3, acc[3], 0, 0, 0);
            acc[3] = __builtin_amdgcn_mfma_f32_16x16x32_bf16(al, wh3, acc[3], 0, 0, 0);
            __builtin_amdgcn_s_setprio(0);
        }

        // ---- h1 = ssp(acc + b1) -> f32, overlays X (same swizzle family) ----
        #pragma unroll
        for (int nt = 0; nt < 4; ++nt)
            #pragma unroll
            for (int r = 0; r < 4; ++r) {
                const int row = crow + r;
                *(float*)(wb + (row << 8) +
                          ((((nt * 16 + n16) << 2)) ^ ((row & 7) << 4))) =
                    ssp(acc[nt][r] + b1v[nt]);
            }

        // ---- matmul 2: h1 @ W2 (truncation-split A rebuilt from f32) ----
        f32x4 acc2[4];
        #pragma unroll
        for (int nt = 0; nt < 4; ++nt) acc2[nt] = (f32x4){0.f, 0.f, 0.f, 0.f};
        #pragma unroll
        for (int k0i = 0; k0i < 2; ++k0i) {
            const int bc = (k0i << 7) + (g << 5);
            const int rb = n16 << 8;
            f32x4 f0 = *(f32x4*)(wb + rb + (bc ^ sw_n));
            f32x4 f1 = *(f32x4*)(wb + rb + ((bc + 16) ^ sw_n));
            u32x4 ahu, alu;
            ahu[0] = pkhi(f0[0], f0[1]); ahu[1] = pkhi(f0[2], f0[3]);
            ahu[2] = pkhi(f1[0], f1[1]); ahu[3] = pkhi(f1[2], f1[3]);
            alu[0] = pklo(f0[0], f0[1]); alu[1] = pklo(f0[2], f0[3]);
            alu[2] = pklo(f1[0], f1[1]); alu[3] = pklo(f1[2], f1[3]);
            s8bf ah = *(s8bf*)&ahu;
            s8bf al = *(s8bf*)&alu;
            s8bf wh0 = WFRAG(16384, 0, k0i), wh1 = WFRAG(16384, 1, k0i),
                 wh2 = WFRAG(16384, 2, k0i), wh3 = WFRAG(16384, 3, k0i);
            s8bf wl0 = WFRAG(24576, 0, k0i), wl1 = WFRAG(24576, 1, k0i),
                 wl2 = WFRAG(24576, 2, k0i), wl3 = WFRAG(24576, 3, k0i);
            __builtin_amdgcn_s_setprio(1);
            acc2[0] = __builtin_amdgcn_mfma_f32_16x16x32_bf16(ah, wh0, acc2[0], 0, 0, 0);
            acc2[0] = __builtin_amdgcn_mfma_f32_16x16x32_bf16(ah, wl0, acc2[0], 0, 0, 0);
            acc2[0] = __builtin_amdgcn_mfma_f32_16x16x32_bf16(al, wh0, acc2[0], 0, 0, 0);
            acc2[1] = __builtin_amdgcn_mfma_f32_16x16x32_bf16(ah, wh1, acc2[1], 0, 0, 0);
            acc2[1] = __builtin_amdgcn_mfma_f32_16x16x32_bf16(ah, wl1, acc2[1], 0, 0, 0);
            acc2[1] = __builtin_amdgcn_mfma_f32_16x16x32_bf16(al, wh1, acc2[1], 0, 0, 0);
            acc2[2] = __builtin_amdgcn_mfma_f32_16x16x32_bf16(ah, wh2, acc2[2], 0, 0, 0);
            acc2[2] = __builtin_amdgcn_mfma_f32_16x16x32_bf16(ah, wl2, acc2[2], 0, 0, 0);
            acc2[2] = __builtin_amdgcn_mfma_f32_16x16x32_bf16(al, wh2, acc2[2], 0, 0, 0);
            acc2[3] = __builtin_amdgcn_mfma_f32_16x16x32_bf16(ah, wh3, acc2[3], 0, 0, 0);
            acc2[3] = __builtin_amdgcn_mfma_f32_16x16x32_bf16(ah, wl3, acc2[3], 0, 0, 0);
            acc2[3] = __builtin_amdgcn_mfma_f32_16x16x32_bf16(al, wh3, acc2[3], 0, 0, 0);
            __builtin_amdgcn_s_setprio(0);
        }

        // ---- w = ssp(acc2 + b2) -> f32, overlays h1 ----
        #pragma unroll
        for (int nt = 0; nt < 4; ++nt)
            #pragma unroll
            for (int r = 0; r < 4; ++r) {
                const int row = crow + r;
                *(float*)(wb + (row << 8) +
                          ((((nt * 16 + n16) << 2)) ^ ((row & 7) << 4))) =
                    ssp(acc2[nt][r] + b2v[nt]);
            }

        // ---- scatter: segmented reduce over sorted dst runs (scalar control) ----
        {
            float accv = 0.f;
            int cur = -1;
            #pragma unroll
            for (int e = 0; e < 16; ++e) {
                if (base + e < E) {
                    const int d = __builtin_amdgcn_readlane(dsv0, e);
                    const float mv = *(const float*)(wb + (e << 8) +
                                        ((lane << 2) ^ ((e & 7) << 4))) * evs[e];
                    if (d != cur) {
                        if (cur >= 0) atomicAdd(&sums[(size_t)cur * 64 + lane], accv);
                        accv = mv; cur = d;
                    } else {
                        accv += mv;
                    }
                }
            }
            if (cur >= 0) atomicAdd(&sums[(size_t)cur * 64 + lane], accv);
        }

        // ---- rotate meta pipeline ----
        eiv0 = eiv1; eiv1 = eiv_n;
        dsv0 = dsv1; dsv1 = dsv_n;
    }
}

// ---- node interaction block: h = sums/max(deg,1); out = ssp(h@W3+b3) ----
__global__ __launch_bounds__(256) void node_kernel(
    const float* __restrict__ sums, const int* __restrict__ hist,
    const float* __restrict__ W3, const float* __restrict__ b3,
    float* __restrict__ out, int N)
{
    __shared__ float sW[64][64];
    __shared__ float sb[64];
    __shared__ float sC[64];
    __shared__ float sX[64][65];

    const int tid = threadIdx.x;
    for (int i = tid; i < 4096; i += 256) sW[i >> 6][i & 63] = W3[i];
    if (tid < 64) sb[tid] = b3[tid];

    const int f4 = (tid & 15) << 2;
    const int e4 = (tid >> 4) << 2;
    const int ntiles = (N + 63) >> 6;

    for (int t = blockIdx.x; t < ntiles; t += gridDim.x) {
        const int base = t << 6;
        __syncthreads();
        if (tid < 64) {
            int gn = base + tid;
            sC[tid] = (gn < N) ? 1.0f / fmaxf((float)hist[gn], 1.0f) : 0.0f;
        }
        __syncthreads();
        #pragma unroll
        for (int k = 0; k < 16; ++k) {
            int idx = (k << 8) + tid;
            int n = idx >> 6, r = idx & 63;
            int gn = base + n;
            sX[n][r] = (gn < N) ? sums[(size_t)gn * 64 + r] * sC[n] : 0.0f;
        }
        __syncthreads();

        float acc[4][4] = {{0.f,0.f,0.f,0.f},{0.f,0.f,0.f,0.f},
                           {0.f,0.f,0.f,0.f},{0.f,0.f,0.f,0.f}};
        #pragma unroll 8
        for (int r = 0; r < 64; ++r) {
            float xv[4];
            #pragma unroll
            for (int i = 0; i < 4; ++i) xv[i] = sX[e4 + i][r];
            float4 w4 = *(const float4*)&sW[r][f4];
            #pragma unroll
            for (int i = 0; i < 4; ++i) {
                acc[i][0] = fmaf(xv[i], w4.x, acc[i][0]);
                acc[i][1] = fmaf(xv[i], w4.y, acc[i][1]);
                acc[i][2] = fmaf(xv[i], w4.z, acc[i][2]);
                acc[i][3] = fmaf(xv[i], w4.w, acc[i][3]);
            }
        }

        #pragma unroll
        for (int i = 0; i < 4; ++i) {
            int gn = base + e4 + i;
            if (gn < N) {
                float4 o;
                o.x = ssp(acc[i][0] + sb[f4 + 0]);
                o.y = ssp(acc[i][1] + sb[f4 + 1]);
                o.z = ssp(acc[i][2] + sb[f4 + 2]);
                o.w = ssp(acc[i][3] + sb[f4 + 3]);
                *(float4*)&out[(size_t)gn * 64 + f4] = o;
            }
        }
    }
}

extern "C" void kernel_launch(void* const* d_in, const int* in_sizes, int n_in,
                              void* d_out, int out_size, void* d_ws, size_t ws_size,
                              hipStream_t stream) {
    const float* bf = (const float*)d_in[0];
    const float* eh = (const float*)d_in[1];
    const float* W1 = (const float*)d_in[2];
    const float* b1 = (const float*)d_in[3];
    const float* W2 = (const float*)d_in[4];
    const float* b2 = (const float*)d_in[5];
    const float* W3 = (const float*)d_in[6];
    const float* b3 = (const float*)d_in[7];
    const int*   dst = (const int*)d_in[8];

    const int E = in_sizes[0] / 64;
    const int N = out_size / 64;        // out is [N, 64]

    // workspace: sums [N*64 f32] | hist N | cursor N | rnk E | meta 2E
    float* sums    = (float*)d_ws;
    int*   hist    = (int*)(sums + (size_t)N * 64);
    int*   cursor  = hist + N;
    int*   rnk     = cursor + N;
    int2*  meta    = (int2*)(rnk + E);

    hipMemsetAsync(d_ws, 0, (size_t)N * 64 * sizeof(float) + N * sizeof(int), stream);

    const int gE4 = (E + 1023) / 1024;
    hist_kernel<<<gE4, 256, 0, stream>>>(dst, hist, rnk, E);
    scan_kernel<<<1, 1024, 0, stream>>>(hist, cursor, N);
    meta_kernel<<<gE4, 256, 0, stream>>>(dst, cursor, rnk, meta, E);

    edge_kernel<<<2048, 256, 0, stream>>>(bf, eh, W1, b1, W2, b2, meta, sums, E);

    const int ntilesN = (N + 63) >> 6;
    node_kernel<<<ntilesN, 256, 0, stream>>>(sums, hist, W3, b3, (float*)d_out, N);
}

// Round 16
// 373.589 us; speedup vs baseline: 1.2316x; 1.2316x over previous
//
#include <hip/hip_runtime.h>
#include <hip/hip_bf16.h>

#define LOG2F_ 0.69314718055994530942f

typedef __attribute__((ext_vector_type(8))) short s8bf;      // 8 bf16 (4 VGPRs)
typedef __attribute__((ext_vector_type(4))) float f32x4;     // MFMA C/D
typedef __attribute__((ext_vector_type(4))) unsigned u32x4;  // 4 packed bf16 pairs

// softplus(x) - log(2), numerically stable
__device__ __forceinline__ float ssp(float x) {
    float e = __expf(-fabsf(x));
    return __logf(1.0f + e) + fmaxf(x, 0.0f) - LOG2F_;
}
__device__ __forceinline__ short bf_hi(float x) {
    __hip_bfloat16 h = __float2bfloat16(x);
    return *reinterpret_cast<short*>(&h);
}
__device__ __forceinline__ float bf_to_f(short s) {
    __hip_bfloat16 h;
    *reinterpret_cast<short*>(&h) = s;
    return __bfloat162float(h);
}
// truncation-split packers (hi rounding irrelevant, lo absorbs it)
__device__ __forceinline__ unsigned pkhi(float a, float b) {
    return (__float_as_uint(a) >> 16) | (__float_as_uint(b) & 0xFFFF0000u);
}
__device__ __forceinline__ unsigned pklo(float a, float b) {
    float ra = a - __uint_as_float(__float_as_uint(a) & 0xFFFF0000u);
    float rb = b - __uint_as_float(__float_as_uint(b) & 0xFFFF0000u);
    return (__float_as_uint(ra) >> 16) | (__float_as_uint(rb) & 0xFFFF0000u);
}

// ---- sort pipeline ----
// pass 1: histogram; atomic RETURN is the intra-bin rank (stored per edge)
__global__ __launch_bounds__(256) void hist_kernel(const int* __restrict__ dst,
                                                   int* __restrict__ hist,
                                                   int* __restrict__ rnk, int E) {
    const int i0 = (blockIdx.x * blockDim.x + threadIdx.x) * 4;
    if (i0 + 3 < E) {
        int4 d = *(const int4*)(dst + i0);
        int4 r;
        r.x = atomicAdd(&hist[d.x], 1);
        r.y = atomicAdd(&hist[d.y], 1);
        r.z = atomicAdd(&hist[d.z], 1);
        r.w = atomicAdd(&hist[d.w], 1);
        *(int4*)(rnk + i0) = r;
    } else {
        for (int j = 0; j < 4; ++j)
            if (i0 + j < E) rnk[i0 + j] = atomicAdd(&hist[dst[i0 + j]], 1);
    }
}

__global__ __launch_bounds__(256) void scan_part(const int* __restrict__ h,
                                                 int* __restrict__ bsum, int N) {
    const int i0 = blockIdx.x * 1024 + threadIdx.x * 4;
    int s = 0;
    #pragma unroll
    for (int j = 0; j < 4; ++j) { int i = i0 + j; if (i < N) s += h[i]; }
    __shared__ int red[4];
    const int lane = threadIdx.x & 63, w = threadIdx.x >> 6;
    #pragma unroll
    for (int off = 32; off; off >>= 1) s += __shfl_down(s, off, 64);
    if (lane == 0) red[w] = s;
    __syncthreads();
    if (threadIdx.x == 0) bsum[blockIdx.x] = red[0] + red[1] + red[2] + red[3];
}

__global__ void scan_top(int* __restrict__ bsum, int nb) {
    const int lane = threadIdx.x;
    if (nb <= 64) {
        int v = (lane < nb) ? bsum[lane] : 0;
        int inc = v;
        #pragma unroll
        for (int off = 1; off < 64; off <<= 1) {
            int o = __shfl_up(inc, off, 64);
            if (lane >= off) inc += o;
        }
        if (lane < nb) bsum[lane] = inc - v;
    } else if (lane == 0) {
        int run = 0;
        for (int i = 0; i < nb; ++i) { int t = bsum[i]; bsum[i] = run; run += t; }
    }
}

__global__ __launch_bounds__(256) void scan_local(const int* __restrict__ h,
                                                  const int* __restrict__ bsum,
                                                  int* __restrict__ cursor, int N) {
    const int i0 = blockIdx.x * 1024 + threadIdx.x * 4;
    int v[4]; int s = 0;
    #pragma unroll
    for (int j = 0; j < 4; ++j) { int i = i0 + j; v[j] = (i < N) ? h[i] : 0; s += v[j]; }
    const int lane = threadIdx.x & 63, w = threadIdx.x >> 6;
    int inc = s;
    #pragma unroll
    for (int off = 1; off < 64; off <<= 1) {
        int o = __shfl_up(inc, off, 64);
        if (lane >= off) inc += o;
    }
    __shared__ int wsum[4];
    if (lane == 63) wsum[w] = inc;
    __syncthreads();
    int run = bsum[blockIdx.x];
    for (int i = 0; i < w; ++i) run += wsum[i];
    run += inc - s;
    #pragma unroll
    for (int j = 0; j < 4; ++j) { int i = i0 + j; if (i < N) cursor[i] = run; run += v[j]; }
}

// pass 2 (NO atomics): p = cursor[dst[e]] + rnk[e]; meta[p] = {e, dst}
__global__ __launch_bounds__(256) void meta_kernel(const int* __restrict__ dst,
                                                   const int* __restrict__ cursor,
                                                   const int* __restrict__ rnk,
                                                   int2* __restrict__ meta, int E) {
    const int i0 = (blockIdx.x * blockDim.x + threadIdx.x) * 4;
    if (i0 + 3 < E) {
        int4 d = *(const int4*)(dst + i0);
        int4 r = *(const int4*)(rnk + i0);
        meta[cursor[d.x] + r.x] = make_int2(i0,     d.x);
        meta[cursor[d.y] + r.y] = make_int2(i0 + 1, d.y);
        meta[cursor[d.z] + r.z] = make_int2(i0 + 2, d.z);
        meta[cursor[d.w] + r.w] = make_int2(i0 + 3, d.w);
    } else {
        for (int j = 0; j < 4; ++j)
            if (i0 + j < E) {
                int dd = dst[i0 + j];
                meta[cursor[dd] + rnk[i0 + j]] = make_int2(i0 + j, dd);
            }
    }
}

// weight fragment read: frag (nt,k0i) of matrix at byte base `woff`,
// linear-in-lane -> canonical conflict-free ds_read_b128
#define WFRAG(woff, nt, k0i) \
    (*(const s8bf*)(lds + (woff) + ((((nt) << 1) + (k0i)) << 10) + (lane << 4)))

// ---- edge filter network over SORTED edges (best-known structure) ----
// LDS: [0,32K) split weights | [32K,48K) 4 waves x 4KB X buffers
// grid = 768 (exactly 3 resident blocks/CU) -> single weight-init per slot.
__global__ __launch_bounds__(256, 3) void edge_kernel(
    const float* __restrict__ bf, const float* __restrict__ eh,
    const float* __restrict__ W1, const float* __restrict__ b1,
    const float* __restrict__ W2, const float* __restrict__ b2,
    const int2* __restrict__ meta,
    float* __restrict__ sums, int E)
{
    __shared__ __align__(16) unsigned char lds[49152];

    const int tid  = threadIdx.x;
    const int lane = tid & 63;
    const int wv   = tid >> 6;
    const int g    = lane >> 4;
    const int n16  = lane & 15;

    // ---- init: build W1/W2 bf16-split B-fragments into LDS ----
    {
        float* wst = (float*)(lds + 32768);
        for (int i = tid; i < 4096; i += 256) wst[i] = W1[i];
        __syncthreads();
        for (int u = tid; u < 512; u += 256) {
            const int f = u >> 6, nt = f >> 1, k0i = f & 1;
            const int gg = (u >> 4) & 3, nn = u & 15;
            s8bf hi, lo;
            #pragma unroll
            for (int j = 0; j < 8; ++j) {
                float v = wst[(k0i * 32 + gg * 8 + j) * 64 + nt * 16 + nn];
                short h = bf_hi(v);
                hi[j] = h; lo[j] = bf_hi(v - bf_to_f(h));
            }
            *(s8bf*)(lds + (u << 4)) = hi;
            *(s8bf*)(lds + 8192 + (u << 4)) = lo;
        }
        __syncthreads();
        for (int i = tid; i < 4096; i += 256) wst[i] = W2[i];
        __syncthreads();
        for (int u = tid; u < 512; u += 256) {
            const int f = u >> 6, nt = f >> 1, k0i = f & 1;
            const int gg = (u >> 4) & 3, nn = u & 15;
            s8bf hi, lo;
            #pragma unroll
            for (int j = 0; j < 8; ++j) {
                float v = wst[(k0i * 32 + gg * 8 + j) * 64 + nt * 16 + nn];
                short h = bf_hi(v);
                hi[j] = h; lo[j] = bf_hi(v - bf_to_f(h));
            }
            *(s8bf*)(lds + 16384 + (u << 4)) = hi;
            *(s8bf*)(lds + 24576 + (u << 4)) = lo;
        }
        __syncthreads();   // last barrier — main loop is barrier-free
    }

    float b1v[4], b2v[4];
    #pragma unroll
    for (int nt = 0; nt < 4; ++nt) { b1v[nt] = b1[nt*16 + n16]; b2v[nt] = b2[nt*16 + n16]; }

    unsigned char* wb = lds + 32768 + (wv << 12);
    char* Xh = (char*)wb;
    char* Xl = (char*)wb + 2048;

    const int r4   = lane >> 2;
    const int c16  = (lane & 3) << 4;
    const int s0   = (lane & 3) << 1;
    const int crow = g << 2;
    const int sw_n = (n16 & 7) << 4;

    const int wave_id = (blockIdx.x << 2) + wv;
    const int nwaves  = gridDim.x << 2;
    const int ntiles  = (E + 15) >> 4;
    const int lastE   = E - 1;

    // ---- prologue: meta 2-deep (coalesced int2), first tile's bf rows ----
    int eiv0 = 0, eiv1 = 0, dsv0 = 0, dsv1 = 0;
    float xs[16];
    {
        const int t1 = wave_id + nwaves;
        if (lane < 16) {
            if (wave_id < ntiles) {
                const int2 mv = meta[min(wave_id * 16 + lane, lastE)];
                eiv0 = mv.x; dsv0 = mv.y;
            }
            if (t1 < ntiles) {
                const int2 mv = meta[min(t1 * 16 + lane, lastE)];
                eiv1 = mv.x; dsv1 = mv.y;
            }
        }
        if (wave_id < ntiles) {
            const int ri = __shfl(eiv0, r4, 64);
            const size_t roff = (size_t)(unsigned)ri * 64 + c16;
            *(float4*)&xs[0]  = *(const float4*)(bf + roff);
            *(float4*)&xs[4]  = *(const float4*)(bf + roff + 4);
            *(float4*)&xs[8]  = *(const float4*)(bf + roff + 8);
            *(float4*)&xs[12] = *(const float4*)(bf + roff + 12);
        }
    }

    for (int t = wave_id; t < ntiles; t += nwaves) {
        const int base = t << 4;

        // ---- truncation-split current X, stage to LDS (packed u32) ----
        u32x4 hv0, hv1, lv0, lv1;
        #pragma unroll
        for (int j = 0; j < 4; ++j) {
            hv0[j] = pkhi(xs[2*j],     xs[2*j + 1]);
            lv0[j] = pklo(xs[2*j],     xs[2*j + 1]);
            hv1[j] = pkhi(xs[8 + 2*j], xs[8 + 2*j + 1]);
            lv1[j] = pklo(xs[8 + 2*j], xs[8 + 2*j + 1]);
        }
        {
            const int sw = (r4 & 7) << 4;
            const int a0 = r4 * 128 + ((s0 << 4) ^ sw);
            const int a1 = r4 * 128 + (((s0 + 1) << 4) ^ sw);
            *(u32x4*)(Xh + a0) = hv0;  *(u32x4*)(Xh + a1) = hv1;
            *(u32x4*)(Xl + a0) = lv0;  *(u32x4*)(Xl + a1) = lv1;
        }

        // ---- eh loads for THIS tile (scalar row base via readlane) ----
        float evs[16];
        #pragma unroll
        for (int e = 0; e < 16; ++e) {
            const int ei = __builtin_amdgcn_readlane(eiv0, e);
            evs[e] = eh[(size_t)(unsigned)ei * 64 + lane];
        }

        // ---- prefetch next tile's bf rows ----
        const int tn1 = t + nwaves, tn2 = t + 2 * nwaves;
        if (tn1 < ntiles) {
            const int ri = __shfl(eiv1, r4, 64);
            const size_t roff = (size_t)(unsigned)ri * 64 + c16;
            *(float4*)&xs[0]  = *(const float4*)(bf + roff);
            *(float4*)&xs[4]  = *(const float4*)(bf + roff + 4);
            *(float4*)&xs[8]  = *(const float4*)(bf + roff + 8);
            *(float4*)&xs[12] = *(const float4*)(bf + roff + 12);
        }

        // ---- advance meta pipeline (coalesced, 2-deep) ----
        int eiv_n = 0, dsv_n = 0;
        if (lane < 16 && tn2 < ntiles) {
            const int2 mv = meta[min(tn2 * 16 + lane, lastE)];
            eiv_n = mv.x; dsv_n = mv.y;
        }

        // ---- matmul 1: X @ W1 (hh + hl + lh); B-frags from LDS ----
        f32x4 acc[4];
        #pragma unroll
        for (int nt = 0; nt < 4; ++nt) acc[nt] = (f32x4){0.f, 0.f, 0.f, 0.f};
        #pragma unroll
        for (int k0i = 0; k0i < 2; ++k0i) {
            const int ab = (n16 << 7) + (((((k0i << 2) + g)) << 4) ^ sw_n);
            s8bf ah = *(s8bf*)(Xh + ab);
            s8bf al = *(s8bf*)(Xl + ab);
            s8bf wh0 = WFRAG(0, 0, k0i), wh1 = WFRAG(0, 1, k0i),
                 wh2 = WFRAG(0, 2, k0i), wh3 = WFRAG(0, 3, k0i);
            s8bf wl0 = WFRAG(8192, 0, k0i), wl1 = WFRAG(8192, 1, k0i),
                 wl2 = WFRAG(8192, 2, k0i), wl3 = WFRAG(8192, 3, k0i);
            __builtin_amdgcn_s_setprio(1);
            acc[0] = __builtin_amdgcn_mfma_f32_16x16x32_bf16(ah, wh0, acc[0], 0, 0, 0);
            acc[0] = __builtin_amdgcn_mfma_f32_16x16x32_bf16(ah, wl0, acc[0], 0, 0, 0);
            acc[0] = __builtin_amdgcn_mfma_f32_16x16x32_bf16(al, wh0, acc[0], 0, 0, 0);
            acc[1] = __builtin_amdgcn_mfma_f32_16x16x32_bf16(ah, wh1, acc[1], 0, 0, 0);
            acc[1] = __builtin_amdgcn_mfma_f32_16x16x32_bf16(ah, wl1, acc[1], 0, 0, 0);
            acc[1] = __builtin_amdgcn_mfma_f32_16x16x32_bf16(al, wh1, acc[1], 0, 0, 0);
            acc[2] = __builtin_amdgcn_mfma_f32_16x16x32_bf16(ah, wh2, acc[2], 0, 0, 0);
            acc[2] = __builtin_amdgcn_mfma_f32_16x16x32_bf16(ah, wl2, acc[2], 0, 0, 0);
            acc[2] = __builtin_amdgcn_mfma_f32_16x16x32_bf16(al, wh2, acc[2], 0, 0, 0);
            acc[3] = __builtin_amdgcn_mfma_f32_16x16x32_bf16(ah, wh3, acc[3], 0, 0, 0);
            acc[3] = __builtin_amdgcn_mfma_f32_16x16x32_bf16(ah, wl3, acc[3], 0, 0, 0);
            acc[3] = __builtin_amdgcn_mfma_f32_16x16x32_bf16(al, wh3, acc[3], 0, 0, 0);
            __builtin_amdgcn_s_setprio(0);
        }

        // ---- h1 = ssp(acc + b1) -> f32, overlays X (same swizzle family) ----
        #pragma unroll
        for (int nt = 0; nt < 4; ++nt)
            #pragma unroll
            for (int r = 0; r < 4; ++r) {
                const int row = crow + r;
                *(float*)(wb + (row << 8) +
                          ((((nt * 16 + n16) << 2)) ^ ((row & 7) << 4))) =
                    ssp(acc[nt][r] + b1v[nt]);
            }

        // ---- matmul 2: h1 @ W2 (truncation-split A rebuilt from f32) ----
        f32x4 acc2[4];
        #pragma unroll
        for (int nt = 0; nt < 4; ++nt) acc2[nt] = (f32x4){0.f, 0.f, 0.f, 0.f};
        #pragma unroll
        for (int k0i = 0; k0i < 2; ++k0i) {
            const int bc = (k0i << 7) + (g << 5);
            const int rb = n16 << 8;
            f32x4 f0 = *(f32x4*)(wb + rb + (bc ^ sw_n));
            f32x4 f1 = *(f32x4*)(wb + rb + ((bc + 16) ^ sw_n));
            u32x4 ahu, alu;
            ahu[0] = pkhi(f0[0], f0[1]); ahu[1] = pkhi(f0[2], f0[3]);
            ahu[2] = pkhi(f1[0], f1[1]); ahu[3] = pkhi(f1[2], f1[3]);
            alu[0] = pklo(f0[0], f0[1]); alu[1] = pklo(f0[2], f0[3]);
            alu[2] = pklo(f1[0], f1[1]); alu[3] = pklo(f1[2], f1[3]);
            s8bf ah = *(s8bf*)&ahu;
            s8bf al = *(s8bf*)&alu;
            s8bf wh0 = WFRAG(16384, 0, k0i), wh1 = WFRAG(16384, 1, k0i),
                 wh2 = WFRAG(16384, 2, k0i), wh3 = WFRAG(16384, 3, k0i);
            s8bf wl0 = WFRAG(24576, 0, k0i), wl1 = WFRAG(24576, 1, k0i),
                 wl2 = WFRAG(24576, 2, k0i), wl3 = WFRAG(24576, 3, k0i);
            __builtin_amdgcn_s_setprio(1);
            acc2[0] = __builtin_amdgcn_mfma_f32_16x16x32_bf16(ah, wh0, acc2[0], 0, 0, 0);
            acc2[0] = __builtin_amdgcn_mfma_f32_16x16x32_bf16(ah, wl0, acc2[0], 0, 0, 0);
            acc2[0] = __builtin_amdgcn_mfma_f32_16x16x32_bf16(al, wh0, acc2[0], 0, 0, 0);
            acc2[1] = __builtin_amdgcn_mfma_f32_16x16x32_bf16(ah, wh1, acc2[1], 0, 0, 0);
            acc2[1] = __builtin_amdgcn_mfma_f32_16x16x32_bf16(ah, wl1, acc2[1], 0, 0, 0);
            acc2[1] = __builtin_amdgcn_mfma_f32_16x16x32_bf16(al, wh1, acc2[1], 0, 0, 0);
            acc2[2] = __builtin_amdgcn_mfma_f32_16x16x32_bf16(ah, wh2, acc2[2], 0, 0, 0);
            acc2[2] = __builtin_amdgcn_mfma_f32_16x16x32_bf16(ah, wl2, acc2[2], 0, 0, 0);
            acc2[2] = __builtin_amdgcn_mfma_f32_16x16x32_bf16(al, wh2, acc2[2], 0, 0, 0);
            acc2[3] = __builtin_amdgcn_mfma_f32_16x16x32_bf16(ah, wh3, acc2[3], 0, 0, 0);
            acc2[3] = __builtin_amdgcn_mfma_f32_16x16x32_bf16(ah, wl3, acc2[3], 0, 0, 0);
            acc2[3] = __builtin_amdgcn_mfma_f32_16x16x32_bf16(al, wh3, acc2[3], 0, 0, 0);
            __builtin_amdgcn_s_setprio(0);
        }

        // ---- w = ssp(acc2 + b2) -> f32, overlays h1 ----
        #pragma unroll
        for (int nt = 0; nt < 4; ++nt)
            #pragma unroll
            for (int r = 0; r < 4; ++r) {
                const int row = crow + r;
                *(float*)(wb + (row << 8) +
                          ((((nt * 16 + n16) << 2)) ^ ((row & 7) << 4))) =
                    ssp(acc2[nt][r] + b2v[nt]);
            }

        // ---- scatter: segmented reduce over sorted dst runs (scalar control) ----
        {
            float accv = 0.f;
            int cur = -1;
            #pragma unroll
            for (int e = 0; e < 16; ++e) {
                if (base + e < E) {
                    const int d = __builtin_amdgcn_readlane(dsv0, e);
                    const float mv = *(const float*)(wb + (e << 8) +
                                        ((lane << 2) ^ ((e & 7) << 4))) * evs[e];
                    if (d != cur) {
                        if (cur >= 0) atomicAdd(&sums[(size_t)cur * 64 + lane], accv);
                        accv = mv; cur = d;
                    } else {
                        accv += mv;
                    }
                }
            }
            if (cur >= 0) atomicAdd(&sums[(size_t)cur * 64 + lane], accv);
        }

        // ---- rotate meta pipeline ----
        eiv0 = eiv1; eiv1 = eiv_n;
        dsv0 = dsv1; dsv1 = dsv_n;
    }
}

// ---- node interaction block: h = sums/max(deg,1); out = ssp(h@W3+b3) ----
__global__ __launch_bounds__(256) void node_kernel(
    const float* __restrict__ sums, const int* __restrict__ hist,
    const float* __restrict__ W3, const float* __restrict__ b3,
    float* __restrict__ out, int N)
{
    __shared__ float sW[64][64];
    __shared__ float sb[64];
    __shared__ float sC[64];
    __shared__ float sX[64][65];

    const int tid = threadIdx.x;
    for (int i = tid; i < 4096; i += 256) sW[i >> 6][i & 63] = W3[i];
    if (tid < 64) sb[tid] = b3[tid];

    const int f4 = (tid & 15) << 2;
    const int e4 = (tid >> 4) << 2;
    const int ntiles = (N + 63) >> 6;

    for (int t = blockIdx.x; t < ntiles; t += gridDim.x) {
        const int base = t << 6;
        __syncthreads();
        if (tid < 64) {
            int gn = base + tid;
            sC[tid] = (gn < N) ? 1.0f / fmaxf((float)hist[gn], 1.0f) : 0.0f;
        }
        __syncthreads();
        #pragma unroll
        for (int k = 0; k < 16; ++k) {
            int idx = (k << 8) + tid;
            int n = idx >> 6, r = idx & 63;
            int gn = base + n;
            sX[n][r] = (gn < N) ? sums[(size_t)gn * 64 + r] * sC[n] : 0.0f;
        }
        __syncthreads();

        float acc[4][4] = {{0.f,0.f,0.f,0.f},{0.f,0.f,0.f,0.f},
                           {0.f,0.f,0.f,0.f},{0.f,0.f,0.f,0.f}};
        #pragma unroll 8
        for (int r = 0; r < 64; ++r) {
            float xv[4];
            #pragma unroll
            for (int i = 0; i < 4; ++i) xv[i] = sX[e4 + i][r];
            float4 w4 = *(const float4*)&sW[r][f4];
            #pragma unroll
            for (int i = 0; i < 4; ++i) {
                acc[i][0] = fmaf(xv[i], w4.x, acc[i][0]);
                acc[i][1] = fmaf(xv[i], w4.y, acc[i][1]);
                acc[i][2] = fmaf(xv[i], w4.z, acc[i][2]);
                acc[i][3] = fmaf(xv[i], w4.w, acc[i][3]);
            }
        }

        #pragma unroll
        for (int i = 0; i < 4; ++i) {
            int gn = base + e4 + i;
            if (gn < N) {
                float4 o;
                o.x = ssp(acc[i][0] + sb[f4 + 0]);
                o.y = ssp(acc[i][1] + sb[f4 + 1]);
                o.z = ssp(acc[i][2] + sb[f4 + 2]);
                o.w = ssp(acc[i][3] + sb[f4 + 3]);
                *(float4*)&out[(size_t)gn * 64 + f4] = o;
            }
        }
    }
}

extern "C" void kernel_launch(void* const* d_in, const int* in_sizes, int n_in,
                              void* d_out, int out_size, void* d_ws, size_t ws_size,
                              hipStream_t stream) {
    const float* bf = (const float*)d_in[0];
    const float* eh = (const float*)d_in[1];
    const float* W1 = (const float*)d_in[2];
    const float* b1 = (const float*)d_in[3];
    const float* W2 = (const float*)d_in[4];
    const float* b2 = (const float*)d_in[5];
    const float* W3 = (const float*)d_in[6];
    const float* b3 = (const float*)d_in[7];
    const int*   dst = (const int*)d_in[8];

    const int E = in_sizes[0] / 64;
    const int N = out_size / 64;        // out is [N, 64]

    // workspace: sums [N*64 f32] | hist N | cursor N | rnk E | meta 2E | bsum
    float* sums    = (float*)d_ws;
    int*   hist    = (int*)(sums + (size_t)N * 64);
    int*   cursor  = hist + N;
    int*   rnk     = cursor + N;
    int2*  meta    = (int2*)(rnk + E);
    int*   bsum    = (int*)(meta + E);

    hipMemsetAsync(d_ws, 0, (size_t)N * 64 * sizeof(float) + N * sizeof(int), stream);

    const int gE4 = (E + 1023) / 1024;
    const int nb  = (N + 1023) >> 10;
    hist_kernel<<<gE4, 256, 0, stream>>>(dst, hist, rnk, E);
    scan_part<<<nb, 256, 0, stream>>>(hist, bsum, N);
    scan_top<<<1, 64, 0, stream>>>(bsum, nb);
    scan_local<<<nb, 256, 0, stream>>>(hist, bsum, cursor, N);
    meta_kernel<<<gE4, 256, 0, stream>>>(dst, cursor, rnk, meta, E);

    edge_kernel<<<768, 256, 0, stream>>>(bf, eh, W1, b1, W2, b2, meta, sums, E);

    const int ntilesN = (N + 63) >> 6;
    node_kernel<<<ntilesN, 256, 0, stream>>>(sums, hist, W3, b3, (float*)d_out, N);
}